// Round 2
// baseline (2206.672 us; speedup 1.0000x reference)
//
#include <hip/hip_runtime.h>
#include <cstdint>
#include <cstddef>

typedef __attribute__((ext_vector_type(8))) short bf16x8;
typedef __attribute__((ext_vector_type(4))) short bf16x4v;
typedef __attribute__((ext_vector_type(4))) float f32x4;

__device__ inline short f2bf(float f) {
  union { float f; unsigned u; } c; c.f = f;
  unsigned u = c.u;
  unsigned r = (u + 0x7fffu + ((u >> 16) & 1u)) >> 16;
  return (short)r;
}
__device__ inline float swish_f(float v) { return v / (1.f + __expf(-v)); }

// ------------------------------------------------------------------
// s1 = embed @ d1_w + d1_b  (4x64);  s2 = context @ d2_w + d2_b (4x128)
__global__ __launch_bounds__(256) void scales_kernel(
    const float* __restrict__ embed, const float* __restrict__ context,
    const float* __restrict__ d1w, const float* __restrict__ d1b,
    const float* __restrict__ d2w, const float* __restrict__ d2b,
    float* __restrict__ s1, float* __restrict__ s2) {
  int tid = blockIdx.x * 256 + threadIdx.x;
  if (tid < 256) {
    int b = tid >> 6, c = tid & 63;
    float acc = d1b[c];
    for (int e = 0; e < 256; ++e) acc += embed[b * 256 + e] * d1w[e * 64 + c];
    s1[tid] = acc;
  } else if (tid < 768) {
    int o = tid - 256;
    int b = o >> 7, c = o & 127;
    float acc = d2b[c];
    for (int e = 0; e < 256; ++e) acc += context[b * 256 + e] * d2w[e * 128 + c];
    s2[o] = acc;
  }
}

// ------------------------------------------------------------------
// Weight repack: w[co][ci][kz][ky][kx] fp32 -> wt[tap][co][ci] bf16
__global__ __launch_bounds__(256) void prep_w_kernel(
    const float* __restrict__ w20, const float* __restrict__ w21,
    const float* __restrict__ wdn, const float* __restrict__ rsw,
    short* __restrict__ wt20, short* __restrict__ wt21,
    short* __restrict__ wtdn, short* __restrict__ rw) {
  for (int o = blockIdx.x * 256 + threadIdx.x; o < 1114112; o += gridDim.x * 256) {
    if (o < 221184) {                       // wt20: 27*128*64
      int t = o >> 13, rem = o & 8191, co = rem >> 6, ci = rem & 63;
      wt20[o] = f2bf(w20[(co * 64 + ci) * 27 + t]);
    } else if (o < 663552) {                // wt21: 27*128*128
      int p = o - 221184;
      int t = p >> 14, rem = p & 16383, co = rem >> 7, ci = rem & 127;
      wt21[p] = f2bf(w21[(co * 128 + ci) * 27 + t]);
    } else if (o < 1105920) {               // wtdn: 27*128*128
      int p = o - 663552;
      int t = p >> 14, rem = p & 16383, co = rem >> 7, ci = rem & 127;
      wtdn[p] = f2bf(wdn[(co * 128 + ci) * 27 + t]);
    } else {                                // rw: 128*64 (1x1x1, same order)
      int p = o - 1105920;
      rw[p] = f2bf(rsw[p]);
    }
  }
}

// ------------------------------------------------------------------
// h1[b][z][y][x][ci] bf16 = swish(x + s1[b][ci]); channels-last via LDS transpose
__global__ __launch_bounds__(256) void prep_h1_kernel(
    const float* __restrict__ xin, const float* __restrict__ s1,
    short* __restrict__ h1) {
  __shared__ __align__(16) short sm[128 * 72];
  const int tid = threadIdx.x;
  const int gid = blockIdx.x;               // = b*1024 + z*128 + y
  const int y = gid & 127, z = (gid >> 7) & 7, b = gid >> 10;
  const float* xbase = xin + (size_t)b * 8388608 + (size_t)z * 16384 + (size_t)y * 128;
#pragma unroll
  for (int i = 0; i < 8; ++i) {             // 2048 float4
    int e = i * 256 + tid;
    int ci = e >> 5, x4 = e & 31;
    float4 v = *(const float4*)(xbase + (size_t)ci * 131072 + x4 * 4);
    float s = s1[b * 64 + ci];
    sm[(x4 * 4 + 0) * 72 + ci] = f2bf(swish_f(v.x + s));
    sm[(x4 * 4 + 1) * 72 + ci] = f2bf(swish_f(v.y + s));
    sm[(x4 * 4 + 2) * 72 + ci] = f2bf(swish_f(v.z + s));
    sm[(x4 * 4 + 3) * 72 + ci] = f2bf(swish_f(v.w + s));
  }
  __syncthreads();
  short* orow = h1 + (size_t)gid * 8192;
#pragma unroll
  for (int i = 0; i < 4; ++i) {             // 1024 vec8
    int e = i * 256 + tid;
    int xx = e >> 3, c8 = e & 7;
    *(bf16x8*)(orow + e * 8) = *(const bf16x8*)(&sm[xx * 72 + c8 * 8]);
  }
}

// ------------------------------------------------------------------
// conv20: h2 = swish(conv3d(h1, w20) + b20) * s2   (Cin=64 -> Cout=128), bf16 out
__global__ __launch_bounds__(256) void conv20_kernel(
    const short* __restrict__ h1, const short* __restrict__ wt,
    const float* __restrict__ b20, const float* __restrict__ s2,
    short* __restrict__ h2) {
  __shared__ __align__(16) short sm[17408];
  const int tid = threadIdx.x;
  // XCD swizzle: each XCD owns a contiguous 16-row y-slab for all (b,z)
  const int bi = blockIdx.x;
  const int xcd = bi & 7, slot = bi >> 3;
  const int yo = slot & 15, z = (slot >> 4) & 7, b = slot >> 7;
  const int y = xcd * 16 + yo;
  const int gid = b * 1024 + z * 128 + y;
  const int lane = tid & 63, wave = tid >> 6;
  const int wm = wave >> 1, wn = wave & 1;
  const int q = lane >> 4, n0 = lane & 15;
  f32x4 acc[4][4];
#pragma unroll
  for (int i = 0; i < 4; ++i)
#pragma unroll
    for (int j = 0; j < 4; ++j) acc[i][j] = (f32x4){0.f, 0.f, 0.f, 0.f};
  const bf16x8 zz = {0, 0, 0, 0, 0, 0, 0, 0};

  bf16x8 pv[4];
  auto issue = [&](int it) {
    const int kz = it / 3, ky = it - kz * 3;
    const int zi = z + kz - 1, yi = y + ky - 1;
    if (zi >= 0 && zi < 8 && yi >= 0 && yi < 128) {
      const bf16x8* src = (const bf16x8*)(h1 + ((size_t)(b * 1024 + zi * 128 + yi) << 13));
#pragma unroll
      for (int i = 0; i < 4; ++i) pv[i] = src[i * 256 + tid];
    } else {
#pragma unroll
      for (int i = 0; i < 4; ++i) pv[i] = zz;
    }
  };

  issue(0);
  for (int it = 0; it < 9; ++it) {
    const int kz = it / 3, ky = it - kz * 3;
    __syncthreads();
#pragma unroll
    for (int i = 0; i < 4; ++i) {           // 1024 vec8: [x][ci] -> LDS[(x+1)][ciP]
      int e = i * 256 + tid;
      int xp = e >> 3, c8 = e & 7;
      *(bf16x8*)(&sm[(xp + 1) * 72 + c8 * 8]) = pv[i];
    }
    if (tid < 16) {
      int hf = tid >> 3, c8 = tid & 7;
      *(bf16x8*)(&sm[(hf ? 129 : 0) * 72 + c8 * 8]) = zz;
    }
    __syncthreads();
    if (it < 8) issue(it + 1);              // prefetch next row behind compute
#pragma unroll
    for (int kx = 0; kx < 3; ++kx) {
      const short* wtap = wt + ((kz * 3 + ky) * 3 + kx) * 8192;
#pragma unroll
      for (int ch = 0; ch < 2; ++ch) {
        bf16x8 af[4], bb[4];
#pragma unroll
        for (int i = 0; i < 4; ++i)
          af[i] = *(const bf16x8*)(wtap + (wm * 64 + i * 16 + n0) * 64 + ch * 32 + q * 8);
#pragma unroll
        for (int j = 0; j < 4; ++j)
          bb[j] = *(const bf16x8*)(&sm[(wn * 64 + j * 16 + n0 + kx) * 72 + ch * 32 + q * 8]);
#pragma unroll
        for (int i = 0; i < 4; ++i)
#pragma unroll
          for (int j = 0; j < 4; ++j)
            acc[i][j] = __builtin_amdgcn_mfma_f32_16x16x32_bf16(af[i], bb[j], acc[i][j], 0, 0, 0);
      }
    }
  }
  // epilogue: bias + swish + s2, transpose through LDS, contiguous bf16 row out
  __syncthreads();
#pragma unroll
  for (int i = 0; i < 4; ++i) {
    const int mb = wm * 64 + i * 16 + q * 4;
    const float4 bias = *(const float4*)(b20 + mb);
    const float4 sc = *(const float4*)(s2 + b * 128 + mb);
#pragma unroll
    for (int j = 0; j < 4; ++j) {
      const int n = wn * 64 + j * 16 + n0;
      bf16x4v pk;
      pk.x = f2bf(swish_f(acc[i][j][0] + bias.x) * sc.x);
      pk.y = f2bf(swish_f(acc[i][j][1] + bias.y) * sc.y);
      pk.z = f2bf(swish_f(acc[i][j][2] + bias.z) * sc.z);
      pk.w = f2bf(swish_f(acc[i][j][3] + bias.w) * sc.w);
      *(bf16x4v*)(&sm[n * 136 + mb]) = pk;
    }
  }
  __syncthreads();
  short* orow = h2 + (size_t)gid * 16384;
#pragma unroll
  for (int i = 0; i < 8; ++i) {             // 2048 vec8
    int e = i * 256 + tid;
    int xx = e >> 4, c8 = e & 15;
    *(bf16x8*)(orow + e * 8) = *(const bf16x8*)(&sm[xx * 136 + c8 * 8]);
  }
}

// ------------------------------------------------------------------
// conv21: h3 = swish(conv3d(h2, w21) + conv1x1(x, res_w) + res_b)  (128->128), bf16
__global__ __launch_bounds__(256) void conv21_kernel(
    const short* __restrict__ h2, const short* __restrict__ wt,
    const float* __restrict__ xin, const short* __restrict__ rw,
    const float* __restrict__ res_b, short* __restrict__ h3) {
  __shared__ __align__(16) short sm[17680];
  const int tid = threadIdx.x;
  const int bi = blockIdx.x;
  const int xcd = bi & 7, slot = bi >> 3;
  const int yo = slot & 15, z = (slot >> 4) & 7, b = slot >> 7;
  const int y = xcd * 16 + yo;
  const int gid = b * 1024 + z * 128 + y;
  const int lane = tid & 63, wave = tid >> 6;
  const int wm = wave >> 1, wn = wave & 1;
  const int q = lane >> 4, n0 = lane & 15;
  f32x4 acc[4][4];
#pragma unroll
  for (int i = 0; i < 4; ++i)
#pragma unroll
    for (int j = 0; j < 4; ++j) acc[i][j] = (f32x4){0.f, 0.f, 0.f, 0.f};
  const bf16x8 zz = {0, 0, 0, 0, 0, 0, 0, 0};
  const float* xbase = xin + (size_t)b * 8388608 + (size_t)z * 16384 + (size_t)y * 128;

  bf16x8 pv[8];
  float4 xv[8];
  auto issue = [&](int it) {
    const int kz = it / 3, ky = it - kz * 3;
    const int zi = z + kz - 1, yi = y + ky - 1;
    if (zi >= 0 && zi < 8 && yi >= 0 && yi < 128) {
      const bf16x8* src = (const bf16x8*)(h2 + ((size_t)(b * 1024 + zi * 128 + yi) << 14));
#pragma unroll
      for (int i = 0; i < 8; ++i) pv[i] = src[i * 256 + tid];
    } else {
#pragma unroll
      for (int i = 0; i < 8; ++i) pv[i] = zz;
    }
  };

  issue(0);
  for (int it = 0; it < 9; ++it) {
    const int kz = it / 3, ky = it - kz * 3;
    __syncthreads();
#pragma unroll
    for (int i = 0; i < 8; ++i) {           // 2048 vec8
      int e = i * 256 + tid;
      int xp = e >> 4, c8 = e & 15;
      *(bf16x8*)(&sm[(xp + 1) * 136 + c8 * 8]) = pv[i];
    }
    if (tid < 32) {
      int hf = tid >> 4, c8 = tid & 15;
      *(bf16x8*)(&sm[(hf ? 129 : 0) * 136 + c8 * 8]) = zz;
    }
    __syncthreads();
    if (it < 8) {
      issue(it + 1);                        // prefetch next row behind compute
    } else {
#pragma unroll
      for (int i = 0; i < 8; ++i) {         // prefetch fp32 res row behind last compute
        int e = i * 256 + tid;
        int ci = e >> 5, x4 = e & 31;
        xv[i] = *(const float4*)(xbase + (size_t)ci * 131072 + x4 * 4);
      }
    }
#pragma unroll
    for (int kx = 0; kx < 3; ++kx) {
      const short* wtap = wt + ((kz * 3 + ky) * 3 + kx) * 16384;
#pragma unroll
      for (int ch = 0; ch < 4; ++ch) {
        bf16x8 af[4], bb[4];
#pragma unroll
        for (int i = 0; i < 4; ++i)
          af[i] = *(const bf16x8*)(wtap + (wm * 64 + i * 16 + n0) * 128 + ch * 32 + q * 8);
#pragma unroll
        for (int j = 0; j < 4; ++j)
          bb[j] = *(const bf16x8*)(&sm[(wn * 64 + j * 16 + n0 + kx) * 136 + ch * 32 + q * 8]);
#pragma unroll
        for (int i = 0; i < 4; ++i)
#pragma unroll
          for (int j = 0; j < 4; ++j)
            acc[i][j] = __builtin_amdgcn_mfma_f32_16x16x32_bf16(af[i], bb[j], acc[i][j], 0, 0, 0);
      }
    }
  }
  // res tap: 1x1x1 conv of original x (prefetched fp32) -> in-LDS transpose
  __syncthreads();
#pragma unroll
  for (int i = 0; i < 8; ++i) {
    int e = i * 256 + tid;
    int ci = e >> 5, x4 = e & 31;
    sm[(x4 * 4 + 0) * 136 + ci] = f2bf(xv[i].x);
    sm[(x4 * 4 + 1) * 136 + ci] = f2bf(xv[i].y);
    sm[(x4 * 4 + 2) * 136 + ci] = f2bf(xv[i].z);
    sm[(x4 * 4 + 3) * 136 + ci] = f2bf(xv[i].w);
  }
  __syncthreads();
#pragma unroll
  for (int ch = 0; ch < 2; ++ch) {
    bf16x8 af[4], bb[4];
#pragma unroll
    for (int i = 0; i < 4; ++i)
      af[i] = *(const bf16x8*)(rw + (wm * 64 + i * 16 + n0) * 64 + ch * 32 + q * 8);
#pragma unroll
    for (int j = 0; j < 4; ++j)
      bb[j] = *(const bf16x8*)(&sm[(wn * 64 + j * 16 + n0) * 136 + ch * 32 + q * 8]);
#pragma unroll
    for (int i = 0; i < 4; ++i)
#pragma unroll
      for (int j = 0; j < 4; ++j)
        acc[i][j] = __builtin_amdgcn_mfma_f32_16x16x32_bf16(af[i], bb[j], acc[i][j], 0, 0, 0);
  }
  // epilogue: + res_b, swish, bf16 out (channels-last)
  __syncthreads();
#pragma unroll
  for (int i = 0; i < 4; ++i) {
    const int mb = wm * 64 + i * 16 + q * 4;
    const float4 bias = *(const float4*)(res_b + mb);
#pragma unroll
    for (int j = 0; j < 4; ++j) {
      const int n = wn * 64 + j * 16 + n0;
      bf16x4v pk;
      pk.x = f2bf(swish_f(acc[i][j][0] + bias.x));
      pk.y = f2bf(swish_f(acc[i][j][1] + bias.y));
      pk.z = f2bf(swish_f(acc[i][j][2] + bias.z));
      pk.w = f2bf(swish_f(acc[i][j][3] + bias.w));
      *(bf16x4v*)(&sm[n * 136 + mb]) = pk;
    }
  }
  __syncthreads();
  short* orow = h3 + (size_t)gid * 16384;
#pragma unroll
  for (int i = 0; i < 8; ++i) {
    int e = i * 256 + tid;
    int xx = e >> 4, c8 = e & 15;
    *(bf16x8*)(orow + e * 8) = *(const bf16x8*)(&sm[xx * 136 + c8 * 8]);
  }
}

// ------------------------------------------------------------------
// down: out = conv3d(h3, down_w, stride (1,2,2), pad z only) + down_b, fp32 NCDHW
__global__ __launch_bounds__(256) void down_kernel(
    const short* __restrict__ h3, const short* __restrict__ wt,
    const float* __restrict__ dnb, float* __restrict__ out) {
  __shared__ __align__(16) short sm[17680];
  const int tid = threadIdx.x;
  // XCD swizzle: contiguous output-index range per XCD
  const int bi = blockIdx.x;                // 4*8*63 = 2016
  const int o = (bi & 7) * 252 + (bi >> 3);
  const int yo = o % 63;
  const int zb = o / 63;
  const int z = zb & 7, b = zb >> 3;
  const int lane = tid & 63, wave = tid >> 6;
  const int wm = wave >> 1, wn = wave & 1;  // wm: co half, wn: n half (32 each)
  const int q = lane >> 4, n0 = lane & 15;
  f32x4 acc[4][2];
#pragma unroll
  for (int i = 0; i < 4; ++i)
#pragma unroll
    for (int j = 0; j < 2; ++j) acc[i][j] = (f32x4){0.f, 0.f, 0.f, 0.f};
  const bf16x8 zz = {0, 0, 0, 0, 0, 0, 0, 0};

  bf16x8 pv[8];
  auto issue = [&](int it) {
    const int kz = it / 3, ky = it - kz * 3;
    const int zi = z + kz - 1;
    const int yi = 2 * yo + ky;             // always in [0,127)
    if (zi >= 0 && zi < 8) {
      const bf16x8* src = (const bf16x8*)(h3 + ((size_t)(b * 1024 + zi * 128 + yi) << 14));
#pragma unroll
      for (int i = 0; i < 8; ++i) pv[i] = src[i * 256 + tid];
    } else {
#pragma unroll
      for (int i = 0; i < 8; ++i) pv[i] = zz;
    }
  };

  issue(0);
  for (int it = 0; it < 9; ++it) {
    const int kz = it / 3, ky = it - kz * 3;
    __syncthreads();
#pragma unroll
    for (int i = 0; i < 8; ++i) {           // 2048 vec8, xp = x (no shift)
      int e = i * 256 + tid;
      int xp = e >> 4, c8 = e & 15;
      *(bf16x8*)(&sm[xp * 136 + c8 * 8]) = pv[i];
    }
    if (tid < 32) {                         // zero xp = 128,129 (read by dead n=63 lanes)
      int hf = tid >> 4, c8 = tid & 15;
      *(bf16x8*)(&sm[(128 + hf) * 136 + c8 * 8]) = zz;
    }
    __syncthreads();
    if (it < 8) issue(it + 1);
#pragma unroll
    for (int kx = 0; kx < 3; ++kx) {
      const short* wtap = wt + ((kz * 3 + ky) * 3 + kx) * 16384;
#pragma unroll
      for (int ch = 0; ch < 4; ++ch) {
        bf16x8 af[4], bb[2];
#pragma unroll
        for (int i = 0; i < 4; ++i)
          af[i] = *(const bf16x8*)(wtap + (wm * 64 + i * 16 + n0) * 128 + ch * 32 + q * 8);
#pragma unroll
        for (int j = 0; j < 2; ++j) {
          int xp = 2 * (wn * 32 + j * 16 + n0) + kx;
          bb[j] = *(const bf16x8*)(&sm[xp * 136 + ch * 32 + q * 8]);
        }
#pragma unroll
        for (int i = 0; i < 4; ++i)
#pragma unroll
          for (int j = 0; j < 2; ++j)
            acc[i][j] = __builtin_amdgcn_mfma_f32_16x16x32_bf16(af[i], bb[j], acc[i][j], 0, 0, 0);
      }
    }
  }
  // epilogue: + down_b, fp32 transpose in LDS, channels-first NCDHW out
  __syncthreads();
  float* fsm = (float*)sm;
#pragma unroll
  for (int i = 0; i < 4; ++i) {
    const int mb = wm * 64 + i * 16 + q * 4;
    const float4 bias = *(const float4*)(dnb + mb);
#pragma unroll
    for (int j = 0; j < 2; ++j) {
      const int n = wn * 32 + j * 16 + n0;
      f32x4 v;
      v[0] = acc[i][j][0] + bias.x;
      v[1] = acc[i][j][1] + bias.y;
      v[2] = acc[i][j][2] + bias.z;
      v[3] = acc[i][j][3] + bias.w;
      *(f32x4*)(&fsm[n * 132 + mb]) = v;
    }
  }
  __syncthreads();
#pragma unroll
  for (int it = 0; it < 32; ++it) {         // 128 co x 64 lanes (63 valid)
    int idx = it * 256 + tid;
    int co = idx >> 6, xl = idx & 63;
    if (xl < 63)
      out[((size_t)(b * 128 + co) * 8 + z) * 3969 + yo * 63 + xl] = fsm[xl * 132 + co];
  }
}

// ------------------------------------------------------------------
extern "C" void kernel_launch(void* const* d_in, const int* in_sizes, int n_in,
                              void* d_out, int out_size, void* d_ws, size_t ws_size,
                              hipStream_t stream) {
  const float* x       = (const float*)d_in[0];
  const float* embed   = (const float*)d_in[1];
  const float* context = (const float*)d_in[2];
  const float* w20     = (const float*)d_in[3];
  const float* b20     = (const float*)d_in[4];
  const float* w21     = (const float*)d_in[5];
  const float* d1w     = (const float*)d_in[6];
  const float* d1b     = (const float*)d_in[7];
  const float* d2w     = (const float*)d_in[8];
  const float* d2b     = (const float*)d_in[9];
  const float* resw    = (const float*)d_in[10];
  const float* resb    = (const float*)d_in[11];
  const float* dnw     = (const float*)d_in[12];
  const float* dnb     = (const float*)d_in[13];
  float* out = (float*)d_out;
  char* ws = (char*)d_ws;
  // ws layout (bytes): total ~322 MB
  float* s1   = (float*)(ws + 0);          // 1 KB
  float* s2   = (float*)(ws + 1024);       // 2 KB
  short* wt20 = (short*)(ws + 4096);       // 432 KB
  short* wt21 = (short*)(ws + 446464);     // 864 KB
  short* wtdn = (short*)(ws + 1331200);    // 864 KB
  short* rw   = (short*)(ws + 2215936);    // 16 KB
  short* h1   = (short*)(ws + 2232320);    // 64 MB  [b][z][y][x][ci=64] bf16
  short* h2   = (short*)(ws + 69341184);   // 128 MB [b][z][y][x][ci=128] bf16
  short* h3   = (short*)(ws + 203558912);  // 128 MB [b][z][y][x][ci=128] bf16

  scales_kernel<<<3, 256, 0, stream>>>(embed, context, d1w, d1b, d2w, d2b, s1, s2);
  prep_w_kernel<<<1088, 256, 0, stream>>>(w20, w21, dnw, resw, wt20, wt21, wtdn, rw);
  prep_h1_kernel<<<4096, 256, 0, stream>>>(x, s1, h1);
  conv20_kernel<<<4096, 256, 0, stream>>>(h1, wt20, b20, s2, h2);
  conv21_kernel<<<4096, 256, 0, stream>>>(h2, wt21, x, rw, resb, h3);
  down_kernel<<<2016, 256, 0, stream>>>(h3, wtdn, dnb, out);
}

// Round 3
// 2079.930 us; speedup vs baseline: 1.0609x; 1.0609x over previous
//
#include <hip/hip_runtime.h>
#include <cstdint>
#include <cstddef>

typedef __attribute__((ext_vector_type(8))) short bf16x8;
typedef __attribute__((ext_vector_type(4))) short bf16x4v;
typedef __attribute__((ext_vector_type(4))) float f32x4;

__device__ inline short f2bf(float f) {
  union { float f; unsigned u; } c; c.f = f;
  unsigned u = c.u;
  unsigned r = (u + 0x7fffu + ((u >> 16) & 1u)) >> 16;
  return (short)r;
}
__device__ inline float swish_f(float v) { return v / (1.f + __expf(-v)); }

__device__ inline void gld_lds16(const void* g, void* l) {
  __builtin_amdgcn_global_load_lds((const __attribute__((address_space(1))) void*)g,
                                   (__attribute__((address_space(3))) void*)l, 16, 0, 0);
}

// ------------------------------------------------------------------
// s1 = embed @ d1_w + d1_b  (4x64);  s2 = context @ d2_w + d2_b (4x128)
__global__ __launch_bounds__(256) void scales_kernel(
    const float* __restrict__ embed, const float* __restrict__ context,
    const float* __restrict__ d1w, const float* __restrict__ d1b,
    const float* __restrict__ d2w, const float* __restrict__ d2b,
    float* __restrict__ s1, float* __restrict__ s2) {
  int tid = blockIdx.x * 256 + threadIdx.x;
  if (tid < 256) {
    int b = tid >> 6, c = tid & 63;
    float acc = d1b[c];
    for (int e = 0; e < 256; ++e) acc += embed[b * 256 + e] * d1w[e * 64 + c];
    s1[tid] = acc;
  } else if (tid < 768) {
    int o = tid - 256;
    int b = o >> 7, c = o & 127;
    float acc = d2b[c];
    for (int e = 0; e < 256; ++e) acc += context[b * 256 + e] * d2w[e * 128 + c];
    s2[o] = acc;
  }
}

// ------------------------------------------------------------------
// Weight repack: w[co][ci][kz][ky][kx] fp32 -> wt[tap][co][ci] bf16
__global__ __launch_bounds__(256) void prep_w_kernel(
    const float* __restrict__ w20, const float* __restrict__ w21,
    const float* __restrict__ wdn, const float* __restrict__ rsw,
    short* __restrict__ wt20, short* __restrict__ wt21,
    short* __restrict__ wtdn, short* __restrict__ rw) {
  for (int o = blockIdx.x * 256 + threadIdx.x; o < 1114112; o += gridDim.x * 256) {
    if (o < 221184) {                       // wt20: 27*128*64
      int t = o >> 13, rem = o & 8191, co = rem >> 6, ci = rem & 63;
      wt20[o] = f2bf(w20[(co * 64 + ci) * 27 + t]);
    } else if (o < 663552) {                // wt21: 27*128*128
      int p = o - 221184;
      int t = p >> 14, rem = p & 16383, co = rem >> 7, ci = rem & 127;
      wt21[p] = f2bf(w21[(co * 128 + ci) * 27 + t]);
    } else if (o < 1105920) {               // wtdn: 27*128*128
      int p = o - 663552;
      int t = p >> 14, rem = p & 16383, co = rem >> 7, ci = rem & 127;
      wtdn[p] = f2bf(wdn[(co * 128 + ci) * 27 + t]);
    } else {                                // rw: 128*64 (1x1x1, same order)
      int p = o - 1105920;
      rw[p] = f2bf(rsw[p]);
    }
  }
}

// ------------------------------------------------------------------
// h1[b][z][y][x][ci] bf16 = swish(x + s1[b][ci]); channels-last via LDS transpose
__global__ __launch_bounds__(256) void prep_h1_kernel(
    const float* __restrict__ xin, const float* __restrict__ s1,
    short* __restrict__ h1) {
  __shared__ __align__(16) short sm[128 * 72];
  const int tid = threadIdx.x;
  const int gid = blockIdx.x;               // = b*1024 + z*128 + y
  const int y = gid & 127, z = (gid >> 7) & 7, b = gid >> 10;
  const float* xbase = xin + (size_t)b * 8388608 + (size_t)z * 16384 + (size_t)y * 128;
#pragma unroll
  for (int i = 0; i < 8; ++i) {             // 2048 float4
    int e = i * 256 + tid;
    int ci = e >> 5, x4 = e & 31;
    float4 v = *(const float4*)(xbase + (size_t)ci * 131072 + x4 * 4);
    float s = s1[b * 64 + ci];
    sm[(x4 * 4 + 0) * 72 + ci] = f2bf(swish_f(v.x + s));
    sm[(x4 * 4 + 1) * 72 + ci] = f2bf(swish_f(v.y + s));
    sm[(x4 * 4 + 2) * 72 + ci] = f2bf(swish_f(v.z + s));
    sm[(x4 * 4 + 3) * 72 + ci] = f2bf(swish_f(v.w + s));
  }
  __syncthreads();
  short* orow = h1 + (size_t)gid * 8192;
#pragma unroll
  for (int i = 0; i < 4; ++i) {             // 1024 vec8
    int e = i * 256 + tid;
    int xx = e >> 3, c8 = e & 7;
    *(bf16x8*)(orow + e * 8) = *(const bf16x8*)(&sm[xx * 72 + c8 * 8]);
  }
}

// ------------------------------------------------------------------
// conv20: h2 = swish(conv3d(h1, w20) + b20) * s2   (Cin=64 -> Cout=128), bf16 out
// LDS: 2 async staging bufs (130 x * 64 ci, xor-swizzled 16B units), dbuf pipeline.
__global__ __launch_bounds__(256, 4) void conv20_kernel(
    const short* __restrict__ h1, const short* __restrict__ wt,
    const float* __restrict__ b20, const float* __restrict__ s2,
    short* __restrict__ h2) {
  __shared__ __align__(16) short sm[17408];   // max(2*8320 staging, 17408 epilogue)
  const int tid = threadIdx.x;
  const int bi = blockIdx.x;
  const int xcd = bi & 7, slot = bi >> 3;
  const int yo = slot & 15, z = (slot >> 4) & 7, b = slot >> 7;
  const int y = xcd * 16 + yo;
  const int gid = b * 1024 + z * 128 + y;
  const int lane = tid & 63, wave = tid >> 6;
  const int wm = wave >> 1, wn = wave & 1;
  const int q = lane >> 4, n0 = lane & 15;
  const bf16x8 zz = {0, 0, 0, 0, 0, 0, 0, 0};
  f32x4 acc[4][4];
#pragma unroll
  for (int i = 0; i < 4; ++i)
#pragma unroll
    for (int j = 0; j < 4; ++j) acc[i][j] = (f32x4){0.f, 0.f, 0.f, 0.f};

  auto stage = [&](short* buf, const short* row) {
#pragma unroll
    for (int i = 0; i < 4; ++i) {           // 16 instrs total, 8 x each
      int x0 = 1 + 8 * (wave * 4 + i);
      int x = x0 + (lane >> 3);
      int c8 = (lane & 7) ^ (x & 7);
      gld_lds16(row + (x - 1) * 64 + c8 * 8, buf + x0 * 64);
    }
  };
  auto zfill = [&](short* buf) {
#pragma unroll
    for (int i = 0; i < 4; ++i)
      *(bf16x8*)(&buf[64 + (i * 256 + tid) * 8]) = zz;
  };

  // halo zeros (phys x=0,129) for both bufs, once
  if (tid < 32) {
    int bsel = tid >> 4, hsel = (tid >> 3) & 1, u = tid & 7;
    *(bf16x8*)(&sm[bsel * 8320 + (hsel ? 8256 : 0) + u * 8]) = zz;
  }
  // prime buf0 with (kz=0,ky=0): zi=z-1, yi=y-1
  {
    const int zi = z - 1, yi = y - 1;
    if (zi >= 0 && yi >= 0)
      stage(sm, h1 + ((size_t)(b * 1024 + zi * 128 + yi) << 13));
    else
      zfill(sm);
  }
  __syncthreads();

  for (int it = 0; it < 9; ++it) {
    short* cur = sm + (it & 1) * 8320;
    short* nxt = sm + ((it + 1) & 1) * 8320;
    if (it < 8) {                           // async-stage next row behind compute
      const int nit = it + 1;
      const int nkz = nit / 3, nky = nit - nkz * 3;
      const int zi = z + nkz - 1, yi = y + nky - 1;
      if (zi >= 0 && zi < 8 && yi >= 0 && yi < 128)
        stage(nxt, h1 + ((size_t)(b * 1024 + zi * 128 + yi) << 13));
      else
        zfill(nxt);
    }
    const int kz = it / 3, ky = it - kz * 3;
#pragma unroll
    for (int kx = 0; kx < 3; ++kx) {
      const short* wtap = wt + ((kz * 3 + ky) * 3 + kx) * 8192;
#pragma unroll
      for (int ch = 0; ch < 2; ++ch) {
        bf16x8 af[4], bb[4];
#pragma unroll
        for (int i = 0; i < 4; ++i)
          af[i] = *(const bf16x8*)(wtap + (wm * 64 + i * 16 + n0) * 64 + ch * 32 + q * 8);
#pragma unroll
        for (int j = 0; j < 4; ++j) {
          int xx = wn * 64 + j * 16 + n0 + kx;
          bb[j] = *(const bf16x8*)(&cur[xx * 64 + (((ch * 4 + q) ^ (xx & 7)) << 3)]);
        }
#pragma unroll
        for (int i = 0; i < 4; ++i)
#pragma unroll
          for (int j = 0; j < 4; ++j)
            acc[i][j] = __builtin_amdgcn_mfma_f32_16x16x32_bf16(af[i], bb[j], acc[i][j], 0, 0, 0);
      }
    }
    __syncthreads();
  }
  // epilogue: bias + swish + s2, transpose through LDS, contiguous bf16 row out
#pragma unroll
  for (int i = 0; i < 4; ++i) {
    const int mb = wm * 64 + i * 16 + q * 4;
    const float4 bias = *(const float4*)(b20 + mb);
    const float4 sc = *(const float4*)(s2 + b * 128 + mb);
#pragma unroll
    for (int j = 0; j < 4; ++j) {
      const int n = wn * 64 + j * 16 + n0;
      bf16x4v pk;
      pk.x = f2bf(swish_f(acc[i][j][0] + bias.x) * sc.x);
      pk.y = f2bf(swish_f(acc[i][j][1] + bias.y) * sc.y);
      pk.z = f2bf(swish_f(acc[i][j][2] + bias.z) * sc.z);
      pk.w = f2bf(swish_f(acc[i][j][3] + bias.w) * sc.w);
      *(bf16x4v*)(&sm[n * 136 + mb]) = pk;
    }
  }
  __syncthreads();
  short* orow = h2 + (size_t)gid * 16384;
#pragma unroll
  for (int i = 0; i < 8; ++i) {             // 2048 vec8
    int e = i * 256 + tid;
    int xx = e >> 4, c8 = e & 15;
    *(bf16x8*)(orow + e * 8) = *(const bf16x8*)(&sm[xx * 136 + c8 * 8]);
  }
}

// ------------------------------------------------------------------
// conv21: h3 = swish(conv3d(h2, w21) + conv1x1(x, res_w) + res_b)  (128->128), bf16
__global__ __launch_bounds__(256, 2) void conv21_kernel(
    const short* __restrict__ h2, const short* __restrict__ wt,
    const float* __restrict__ xin, const short* __restrict__ rw,
    const float* __restrict__ res_b, short* __restrict__ h3) {
  __shared__ __align__(16) short sm[33280];   // 2 bufs of 130x*128ci
  const int tid = threadIdx.x;
  const int bi = blockIdx.x;
  const int xcd = bi & 7, slot = bi >> 3;
  const int yo = slot & 15, z = (slot >> 4) & 7, b = slot >> 7;
  const int y = xcd * 16 + yo;
  const int gid = b * 1024 + z * 128 + y;
  const int lane = tid & 63, wave = tid >> 6;
  const int wm = wave >> 1, wn = wave & 1;
  const int q = lane >> 4, n0 = lane & 15;
  const bf16x8 zz = {0, 0, 0, 0, 0, 0, 0, 0};
  f32x4 acc[4][4];
#pragma unroll
  for (int i = 0; i < 4; ++i)
#pragma unroll
    for (int j = 0; j < 4; ++j) acc[i][j] = (f32x4){0.f, 0.f, 0.f, 0.f};

  auto stage = [&](short* buf, const short* row) {
#pragma unroll
    for (int i = 0; i < 8; ++i) {           // 32 instrs total, 4 x each
      int x0 = 1 + 4 * (wave * 8 + i);
      int x = x0 + (lane >> 4);
      int c8 = (lane & 15) ^ (x & 15);
      gld_lds16(row + (x - 1) * 128 + c8 * 8, buf + x0 * 128);
    }
  };
  auto zfill = [&](short* buf) {
#pragma unroll
    for (int i = 0; i < 8; ++i)
      *(bf16x8*)(&buf[128 + (i * 256 + tid) * 8]) = zz;
  };

  // halo zeros (phys x=0,129) both bufs
  if (tid < 64) {
    int bsel = tid >> 5, hsel = (tid >> 4) & 1, u = tid & 15;
    *(bf16x8*)(&sm[bsel * 16640 + (hsel ? 16512 : 0) + u * 8]) = zz;
  }
  {
    const int zi = z - 1, yi = y - 1;
    if (zi >= 0 && yi >= 0)
      stage(sm, h2 + ((size_t)(b * 1024 + zi * 128 + yi) << 14));
    else
      zfill(sm);
  }
  __syncthreads();

  for (int it = 0; it < 9; ++it) {
    short* cur = sm + (it & 1) * 16640;
    short* nxt = sm + ((it + 1) & 1) * 16640;
    if (it < 8) {
      const int nit = it + 1;
      const int nkz = nit / 3, nky = nit - nkz * 3;
      const int zi = z + nkz - 1, yi = y + nky - 1;
      if (zi >= 0 && zi < 8 && yi >= 0 && yi < 128)
        stage(nxt, h2 + ((size_t)(b * 1024 + zi * 128 + yi) << 14));
      else
        zfill(nxt);
    } else {
      // stage res-tap B (x row, fp32 -> bf16 channels-last, 64-ci swizzled layout)
      const float* xbase = xin + (size_t)b * 8388608 + (size_t)z * 16384 + (size_t)y * 128;
#pragma unroll
      for (int i = 0; i < 8; ++i) {
        int e = i * 256 + tid;
        int ci = e >> 5, x4 = e & 31;
        float4 v = *(const float4*)(xbase + (size_t)ci * 131072 + x4 * 4);
        int u0 = ci >> 3, cl = ci & 7;
#pragma unroll
        for (int k = 0; k < 4; ++k) {
          int xx = x4 * 4 + k;
          float fv = (k == 0) ? v.x : (k == 1) ? v.y : (k == 2) ? v.z : v.w;
          nxt[xx * 64 + ((u0 ^ (xx & 7)) << 3) + cl] = f2bf(fv);
        }
      }
    }
    const int kz = it / 3, ky = it - kz * 3;
#pragma unroll
    for (int kx = 0; kx < 3; ++kx) {
      const short* wtap = wt + ((kz * 3 + ky) * 3 + kx) * 16384;
#pragma unroll
      for (int ch = 0; ch < 4; ++ch) {
        bf16x8 af[4], bb[4];
#pragma unroll
        for (int i = 0; i < 4; ++i)
          af[i] = *(const bf16x8*)(wtap + (wm * 64 + i * 16 + n0) * 128 + ch * 32 + q * 8);
#pragma unroll
        for (int j = 0; j < 4; ++j) {
          int xx = wn * 64 + j * 16 + n0 + kx;
          bb[j] = *(const bf16x8*)(&cur[xx * 128 + (((ch * 4 + q) ^ (xx & 15)) << 3)]);
        }
#pragma unroll
        for (int i = 0; i < 4; ++i)
#pragma unroll
          for (int j = 0; j < 4; ++j)
            acc[i][j] = __builtin_amdgcn_mfma_f32_16x16x32_bf16(af[i], bb[j], acc[i][j], 0, 0, 0);
      }
    }
    __syncthreads();
  }
  // res 1x1 tap: B staged in buf1 (64-ci layout)
  {
    const short* rbuf = sm + 16640;
#pragma unroll
    for (int ch = 0; ch < 2; ++ch) {
      bf16x8 af[4], bb[4];
#pragma unroll
      for (int i = 0; i < 4; ++i)
        af[i] = *(const bf16x8*)(rw + (wm * 64 + i * 16 + n0) * 64 + ch * 32 + q * 8);
#pragma unroll
      for (int j = 0; j < 4; ++j) {
        int xx = wn * 64 + j * 16 + n0;
        bb[j] = *(const bf16x8*)(&rbuf[xx * 64 + (((ch * 4 + q) ^ (xx & 7)) << 3)]);
      }
#pragma unroll
      for (int i = 0; i < 4; ++i)
#pragma unroll
        for (int j = 0; j < 4; ++j)
          acc[i][j] = __builtin_amdgcn_mfma_f32_16x16x32_bf16(af[i], bb[j], acc[i][j], 0, 0, 0);
    }
  }
  __syncthreads();                          // protect bufs before epilogue reuse
  // epilogue: + res_b, swish, bf16 out (channels-last)
#pragma unroll
  for (int i = 0; i < 4; ++i) {
    const int mb = wm * 64 + i * 16 + q * 4;
    const float4 bias = *(const float4*)(res_b + mb);
#pragma unroll
    for (int j = 0; j < 4; ++j) {
      const int n = wn * 64 + j * 16 + n0;
      bf16x4v pk;
      pk.x = f2bf(swish_f(acc[i][j][0] + bias.x));
      pk.y = f2bf(swish_f(acc[i][j][1] + bias.y));
      pk.z = f2bf(swish_f(acc[i][j][2] + bias.z));
      pk.w = f2bf(swish_f(acc[i][j][3] + bias.w));
      *(bf16x4v*)(&sm[n * 136 + mb]) = pk;
    }
  }
  __syncthreads();
  short* orow = h3 + (size_t)gid * 16384;
#pragma unroll
  for (int i = 0; i < 8; ++i) {
    int e = i * 256 + tid;
    int xx = e >> 4, c8 = e & 15;
    *(bf16x8*)(orow + e * 8) = *(const bf16x8*)(&sm[xx * 136 + c8 * 8]);
  }
}

// ------------------------------------------------------------------
// down: out = conv3d(h3, down_w, stride (1,2,2), pad z only) + down_b, fp32 NCDHW
__global__ __launch_bounds__(256, 2) void down_kernel(
    const short* __restrict__ h3, const short* __restrict__ wt,
    const float* __restrict__ dnb, float* __restrict__ out) {
  __shared__ __align__(16) short sm[33280];
  const int tid = threadIdx.x;
  const int bi = blockIdx.x;                // 4*8*63 = 2016
  const int o = (bi & 7) * 252 + (bi >> 3);
  const int yo = o % 63;
  const int zb = o / 63;
  const int z = zb & 7, b = zb >> 3;
  const int lane = tid & 63, wave = tid >> 6;
  const int wm = wave >> 1, wn = wave & 1;
  const int q = lane >> 4, n0 = lane & 15;
  const bf16x8 zz = {0, 0, 0, 0, 0, 0, 0, 0};
  f32x4 acc[4][2];
#pragma unroll
  for (int i = 0; i < 4; ++i)
#pragma unroll
    for (int j = 0; j < 2; ++j) acc[i][j] = (f32x4){0.f, 0.f, 0.f, 0.f};

  auto stage = [&](short* buf, const short* row) {
#pragma unroll
    for (int i = 0; i < 8; ++i) {           // phys x = real x (no shift)
      int x0 = 4 * (wave * 8 + i);
      int x = x0 + (lane >> 4);
      int c8 = (lane & 15) ^ (x & 15);
      gld_lds16(row + x * 128 + c8 * 8, buf + x0 * 128);
    }
  };
  auto zfill = [&](short* buf) {
#pragma unroll
    for (int i = 0; i < 8; ++i)
      *(bf16x8*)(&buf[(i * 256 + tid) * 8]) = zz;
  };

  // zero phys x=128,129 both bufs (read by dead n=63 lanes)
  if (tid < 64) {
    int bsel = tid >> 5, u = tid & 31;
    *(bf16x8*)(&sm[bsel * 16640 + 16384 + u * 8]) = zz;
  }
  {
    const int zi = z - 1, yi = 2 * yo;      // kz=0, ky=0
    if (zi >= 0)
      stage(sm, h3 + ((size_t)(b * 1024 + zi * 128 + yi) << 14));
    else
      zfill(sm);
  }
  __syncthreads();

  for (int it = 0; it < 9; ++it) {
    short* cur = sm + (it & 1) * 16640;
    short* nxt = sm + ((it + 1) & 1) * 16640;
    if (it < 8) {
      const int nit = it + 1;
      const int nkz = nit / 3, nky = nit - nkz * 3;
      const int zi = z + nkz - 1, yi = 2 * yo + nky;
      if (zi >= 0 && zi < 8)
        stage(nxt, h3 + ((size_t)(b * 1024 + zi * 128 + yi) << 14));
      else
        zfill(nxt);
    }
    const int kz = it / 3, ky = it - kz * 3;
#pragma unroll
    for (int kx = 0; kx < 3; ++kx) {
      const short* wtap = wt + ((kz * 3 + ky) * 3 + kx) * 16384;
#pragma unroll
      for (int ch = 0; ch < 4; ++ch) {
        bf16x8 af[4], bb[2];
#pragma unroll
        for (int i = 0; i < 4; ++i)
          af[i] = *(const bf16x8*)(wtap + (wm * 64 + i * 16 + n0) * 128 + ch * 32 + q * 8);
#pragma unroll
        for (int j = 0; j < 2; ++j) {
          int xp = 2 * (wn * 32 + j * 16 + n0) + kx;
          bb[j] = *(const bf16x8*)(&cur[xp * 128 + (((ch * 4 + q) ^ (xp & 15)) << 3)]);
        }
#pragma unroll
        for (int i = 0; i < 4; ++i)
#pragma unroll
          for (int j = 0; j < 2; ++j)
            acc[i][j] = __builtin_amdgcn_mfma_f32_16x16x32_bf16(af[i], bb[j], acc[i][j], 0, 0, 0);
      }
    }
    __syncthreads();
  }
  // epilogue: + down_b, fp32 transpose in LDS, channels-first NCDHW out
  float* fsm = (float*)sm;
#pragma unroll
  for (int i = 0; i < 4; ++i) {
    const int mb = wm * 64 + i * 16 + q * 4;
    const float4 bias = *(const float4*)(dnb + mb);
#pragma unroll
    for (int j = 0; j < 2; ++j) {
      const int n = wn * 32 + j * 16 + n0;
      f32x4 v;
      v[0] = acc[i][j][0] + bias.x;
      v[1] = acc[i][j][1] + bias.y;
      v[2] = acc[i][j][2] + bias.z;
      v[3] = acc[i][j][3] + bias.w;
      *(f32x4*)(&fsm[n * 132 + mb]) = v;
    }
  }
  __syncthreads();
#pragma unroll
  for (int it = 0; it < 32; ++it) {         // 128 co x 64 lanes (63 valid)
    int idx = it * 256 + tid;
    int co = idx >> 6, xl = idx & 63;
    if (xl < 63)
      out[((size_t)(b * 128 + co) * 8 + z) * 3969 + yo * 63 + xl] = fsm[xl * 132 + co];
  }
}

// ------------------------------------------------------------------
extern "C" void kernel_launch(void* const* d_in, const int* in_sizes, int n_in,
                              void* d_out, int out_size, void* d_ws, size_t ws_size,
                              hipStream_t stream) {
  const float* x       = (const float*)d_in[0];
  const float* embed   = (const float*)d_in[1];
  const float* context = (const float*)d_in[2];
  const float* w20     = (const float*)d_in[3];
  const float* b20     = (const float*)d_in[4];
  const float* w21     = (const float*)d_in[5];
  const float* d1w     = (const float*)d_in[6];
  const float* d1b     = (const float*)d_in[7];
  const float* d2w     = (const float*)d_in[8];
  const float* d2b     = (const float*)d_in[9];
  const float* resw    = (const float*)d_in[10];
  const float* resb    = (const float*)d_in[11];
  const float* dnw     = (const float*)d_in[12];
  const float* dnb     = (const float*)d_in[13];
  float* out = (float*)d_out;
  char* ws = (char*)d_ws;
  float* s1   = (float*)(ws + 0);          // 1 KB
  float* s2   = (float*)(ws + 1024);       // 2 KB
  short* wt20 = (short*)(ws + 4096);       // 432 KB
  short* wt21 = (short*)(ws + 446464);     // 864 KB
  short* wtdn = (short*)(ws + 1331200);    // 864 KB
  short* rw   = (short*)(ws + 2215936);    // 16 KB
  short* h1   = (short*)(ws + 2232320);    // 64 MB  [b][z][y][x][ci=64] bf16
  short* h2   = (short*)(ws + 69341184);   // 128 MB [b][z][y][x][ci=128] bf16
  short* h3   = (short*)(ws + 203558912);  // 128 MB [b][z][y][x][ci=128] bf16

  scales_kernel<<<3, 256, 0, stream>>>(embed, context, d1w, d1b, d2w, d2b, s1, s2);
  prep_w_kernel<<<1088, 256, 0, stream>>>(w20, w21, dnw, resw, wt20, wt21, wtdn, rw);
  prep_h1_kernel<<<4096, 256, 0, stream>>>(x, s1, h1);
  conv20_kernel<<<4096, 256, 0, stream>>>(h1, wt20, b20, s2, h2);
  conv21_kernel<<<4096, 256, 0, stream>>>(h2, wt21, x, rw, resb, h3);
  down_kernel<<<2016, 256, 0, stream>>>(h3, wtdn, dnb, out);
}

// Round 4
// 1114.316 us; speedup vs baseline: 1.9803x; 1.8666x over previous
//
#include <hip/hip_runtime.h>
#include <cstdint>
#include <cstddef>

typedef __attribute__((ext_vector_type(8))) short bf16x8;
typedef __attribute__((ext_vector_type(4))) short bf16x4v;
typedef __attribute__((ext_vector_type(4))) float f32x4;

__device__ inline short f2bf(float f) {
  union { float f; unsigned u; } c; c.f = f;
  unsigned u = c.u;
  unsigned r = (u + 0x7fffu + ((u >> 16) & 1u)) >> 16;
  return (short)r;
}
__device__ inline float swish_f(float v) { return v / (1.f + __expf(-v)); }

__device__ inline void gld_lds16(const void* g, void* l) {
  __builtin_amdgcn_global_load_lds((const __attribute__((address_space(1))) void*)g,
                                   (__attribute__((address_space(3))) void*)l, 16, 0, 0);
}

// ------------------------------------------------------------------
// s1 = embed @ d1_w + d1_b  (4x64);  s2 = context @ d2_w + d2_b (4x128)
__global__ __launch_bounds__(256) void scales_kernel(
    const float* __restrict__ embed, const float* __restrict__ context,
    const float* __restrict__ d1w, const float* __restrict__ d1b,
    const float* __restrict__ d2w, const float* __restrict__ d2b,
    float* __restrict__ s1, float* __restrict__ s2) {
  int tid = blockIdx.x * 256 + threadIdx.x;
  if (tid < 256) {
    int b = tid >> 6, c = tid & 63;
    float acc = d1b[c];
    for (int e = 0; e < 256; ++e) acc += embed[b * 256 + e] * d1w[e * 64 + c];
    s1[tid] = acc;
  } else if (tid < 768) {
    int o = tid - 256;
    int b = o >> 7, c = o & 127;
    float acc = d2b[c];
    for (int e = 0; e < 256; ++e) acc += context[b * 256 + e] * d2w[e * 128 + c];
    s2[o] = acc;
  }
}

// ------------------------------------------------------------------
// Weight repack: w[co][ci][kz][ky][kx] fp32 -> wt[tap][co][ci] bf16
__global__ __launch_bounds__(256) void prep_w_kernel(
    const float* __restrict__ w20, const float* __restrict__ w21,
    const float* __restrict__ wdn, const float* __restrict__ rsw,
    short* __restrict__ wt20, short* __restrict__ wt21,
    short* __restrict__ wtdn, short* __restrict__ rw) {
  for (int o = blockIdx.x * 256 + threadIdx.x; o < 1114112; o += gridDim.x * 256) {
    if (o < 221184) {                       // wt20: 27*128*64
      int t = o >> 13, rem = o & 8191, co = rem >> 6, ci = rem & 63;
      wt20[o] = f2bf(w20[(co * 64 + ci) * 27 + t]);
    } else if (o < 663552) {                // wt21: 27*128*128
      int p = o - 221184;
      int t = p >> 14, rem = p & 16383, co = rem >> 7, ci = rem & 127;
      wt21[p] = f2bf(w21[(co * 128 + ci) * 27 + t]);
    } else if (o < 1105920) {               // wtdn: 27*128*128
      int p = o - 663552;
      int t = p >> 14, rem = p & 16383, co = rem >> 7, ci = rem & 127;
      wtdn[p] = f2bf(wdn[(co * 128 + ci) * 27 + t]);
    } else {                                // rw: 128*64 (1x1x1, same order)
      int p = o - 1105920;
      rw[p] = f2bf(rsw[p]);
    }
  }
}

// ------------------------------------------------------------------
// h1[b][z][y][x][ci] bf16 = swish(x + s1[b][ci]); channels-last via LDS transpose
__global__ __launch_bounds__(256) void prep_h1_kernel(
    const float* __restrict__ xin, const float* __restrict__ s1,
    short* __restrict__ h1) {
  __shared__ __align__(16) short sm[128 * 72];
  const int tid = threadIdx.x;
  const int gid = blockIdx.x;               // = b*1024 + z*128 + y
  const int y = gid & 127, z = (gid >> 7) & 7, b = gid >> 10;
  const float* xbase = xin + (size_t)b * 8388608 + (size_t)z * 16384 + (size_t)y * 128;
#pragma unroll
  for (int i = 0; i < 8; ++i) {             // 2048 float4
    int e = i * 256 + tid;
    int ci = e >> 5, x4 = e & 31;
    float4 v = *(const float4*)(xbase + (size_t)ci * 131072 + x4 * 4);
    float s = s1[b * 64 + ci];
    sm[(x4 * 4 + 0) * 72 + ci] = f2bf(swish_f(v.x + s));
    sm[(x4 * 4 + 1) * 72 + ci] = f2bf(swish_f(v.y + s));
    sm[(x4 * 4 + 2) * 72 + ci] = f2bf(swish_f(v.z + s));
    sm[(x4 * 4 + 3) * 72 + ci] = f2bf(swish_f(v.w + s));
  }
  __syncthreads();
  short* orow = h1 + (size_t)gid * 8192;
#pragma unroll
  for (int i = 0; i < 4; ++i) {             // 1024 vec8
    int e = i * 256 + tid;
    int xx = e >> 3, c8 = e & 7;
    *(bf16x8*)(orow + e * 8) = *(const bf16x8*)(&sm[xx * 72 + c8 * 8]);
  }
}

// ------------------------------------------------------------------
// conv20: h2 = swish(conv3d(h1, w20) + b20) * s2   (Cin=64 -> Cout=128), bf16 out
// ALL MFMA operands from LDS: weights DMA'd per full tap (dbuf), input row single-buf.
__global__ __launch_bounds__(256, 3) void conv20_kernel(
    const short* __restrict__ h1, const short* __restrict__ wt,
    const float* __restrict__ b20, const float* __restrict__ s2,
    short* __restrict__ h2) {
  __shared__ __align__(16) short sm[24704];   // inbuf 8320 + wbuf 2*8192
  const int tid = threadIdx.x;
  const int bi = blockIdx.x;
  const int xcd = bi & 7, slot = bi >> 3;
  const int yo = slot & 15, z = (slot >> 4) & 7, b = slot >> 7;
  const int y = xcd * 16 + yo;
  const int gid = b * 1024 + z * 128 + y;
  const int lane = tid & 63, wave = tid >> 6;
  const int wm = wave >> 1, wn = wave & 1;
  const int q = lane >> 4, n0 = lane & 15;
  const bf16x8 zz = {0, 0, 0, 0, 0, 0, 0, 0};
  short* inbuf = sm;                          // [130 x][64 ci], 8-unit xor swizzle
  f32x4 acc[4][4];
#pragma unroll
  for (int i = 0; i < 4; ++i)
#pragma unroll
    for (int j = 0; j < 4; ++j) acc[i][j] = (f32x4){0.f, 0.f, 0.f, 0.f};

  auto wstage = [&](int s) {                  // tap s -> wbuf[s&1]; [co 128][8 units, u^co swz]
    const short* src = wt + (s << 13);
    short* dst = sm + 8320 + ((s & 1) << 13);
    int r = lane >> 3, ss = lane & 7;
#pragma unroll
    for (int i = 0; i < 4; ++i) {
      int c = wave * 4 + i;
      gld_lds16(src + ((c * 8 + r) << 6) + ((ss ^ r) << 3), dst + (c << 9));
    }
  };
  auto instage = [&](int it) {                // row (kz,ky)=it -> inbuf rows 1..128
    int kz = it / 3, ky = it - kz * 3;
    int zi = z + kz - 1, yi = y + ky - 1;
    if (zi >= 0 && zi < 8 && yi >= 0 && yi < 128) {
      const short* row = h1 + ((size_t)(b * 1024 + zi * 128 + yi) << 13);
#pragma unroll
      for (int i = 0; i < 4; ++i) {
        int x0 = 1 + 8 * (wave * 4 + i);
        int x = x0 + (lane >> 3);
        int c8 = (lane & 7) ^ (x & 7);
        gld_lds16(row + ((x - 1) << 6) + (c8 << 3), inbuf + (x0 << 6));
      }
    } else {
#pragma unroll
      for (int i = 0; i < 4; ++i)
        *(bf16x8*)(&inbuf[64 + (i * 256 + tid) * 8]) = zz;
    }
  };

  if (tid < 16) {                             // halo rows 0,129 zero (persist)
    int hf = tid >> 3, u = tid & 7;
    *(bf16x8*)(&inbuf[(hf ? 129 : 0) * 64 + u * 8]) = zz;
  }
  wstage(0);
  instage(0);
  __syncthreads();

  for (int s = 0; s < 27; ++s) {              // step = one tap
    const int it3 = s / 3, kx = s - it3 * 3;
    if (s < 26) wstage(s + 1);
    const short* w = sm + 8320 + ((s & 1) << 13);
#pragma unroll
    for (int ch = 0; ch < 2; ++ch) {
      bf16x8 af[4], bb[4];
#pragma unroll
      for (int i = 0; i < 4; ++i)
        af[i] = *(const bf16x8*)(&w[(wm * 64 + i * 16 + n0) * 64 + (((ch * 4 + q) ^ (n0 & 7)) << 3)]);
#pragma unroll
      for (int j = 0; j < 4; ++j) {
        int xx = wn * 64 + j * 16 + n0 + kx;
        bb[j] = *(const bf16x8*)(&inbuf[xx * 64 + (((ch * 4 + q) ^ (xx & 7)) << 3)]);
      }
#pragma unroll
      for (int i = 0; i < 4; ++i)
#pragma unroll
        for (int j = 0; j < 4; ++j)
          acc[i][j] = __builtin_amdgcn_mfma_f32_16x16x32_bf16(af[i], bb[j], acc[i][j], 0, 0, 0);
    }
    __syncthreads();
    if (kx == 2 && it3 < 8) {                 // iter boundary: restage input row
      instage(it3 + 1);
      __syncthreads();
    }
  }
  // epilogue: bias + swish + s2, transpose through LDS, contiguous bf16 row out
#pragma unroll
  for (int i = 0; i < 4; ++i) {
    const int mb = wm * 64 + i * 16 + q * 4;
    const float4 bias = *(const float4*)(b20 + mb);
    const float4 sc = *(const float4*)(s2 + b * 128 + mb);
#pragma unroll
    for (int j = 0; j < 4; ++j) {
      const int n = wn * 64 + j * 16 + n0;
      bf16x4v pk;
      pk.x = f2bf(swish_f(acc[i][j][0] + bias.x) * sc.x);
      pk.y = f2bf(swish_f(acc[i][j][1] + bias.y) * sc.y);
      pk.z = f2bf(swish_f(acc[i][j][2] + bias.z) * sc.z);
      pk.w = f2bf(swish_f(acc[i][j][3] + bias.w) * sc.w);
      *(bf16x4v*)(&sm[n * 136 + mb]) = pk;
    }
  }
  __syncthreads();
  short* orow = h2 + (size_t)gid * 16384;
#pragma unroll
  for (int i = 0; i < 8; ++i) {               // 2048 vec8
    int e = i * 256 + tid;
    int xx = e >> 4, c8 = e & 15;
    *(bf16x8*)(orow + e * 8) = *(const bf16x8*)(&sm[xx * 136 + c8 * 8]);
  }
}

// ------------------------------------------------------------------
// conv21: h3 = swish(conv3d(h2, w21) + conv1x1(x, res_w) + res_b)  (128->128), bf16
// step = (kx, ci-half): weights 16KB DMA dbuf; input row 33KB single-buf.
__global__ __launch_bounds__(256, 2) void conv21_kernel(
    const short* __restrict__ h2, const short* __restrict__ wt,
    const float* __restrict__ xin, const short* __restrict__ rw,
    const float* __restrict__ res_b, short* __restrict__ h3) {
  __shared__ __align__(16) short sm[33024];   // inbuf 16640 + wbuf 2*8192
  const int tid = threadIdx.x;
  const int bi = blockIdx.x;
  const int xcd = bi & 7, slot = bi >> 3;
  const int yo = slot & 15, z = (slot >> 4) & 7, b = slot >> 7;
  const int y = xcd * 16 + yo;
  const int gid = b * 1024 + z * 128 + y;
  const int lane = tid & 63, wave = tid >> 6;
  const int wm = wave >> 1, wn = wave & 1;
  const int q = lane >> 4, n0 = lane & 15;
  const bf16x8 zz = {0, 0, 0, 0, 0, 0, 0, 0};
  short* inbuf = sm;                          // [130 x][128 ci], 16-unit xor swizzle
  f32x4 acc[4][4];
#pragma unroll
  for (int i = 0; i < 4; ++i)
#pragma unroll
    for (int j = 0; j < 4; ++j) acc[i][j] = (f32x4){0.f, 0.f, 0.f, 0.f};

  auto wstage = [&](int s) {                  // half-tap s -> wbuf[s&1]; [co 128][8 units, u^co]
    int it6 = s / 6, sub = s - it6 * 6, kx = sub >> 1, ch2 = sub & 1;
    const short* src = wt + (((it6 * 3 + kx) << 14) + (ch2 << 6));
    short* dst = sm + 16640 + ((s & 1) << 13);
    int r = lane >> 3, ss = lane & 7;
#pragma unroll
    for (int i = 0; i < 4; ++i) {
      int c = wave * 4 + i;
      gld_lds16(src + ((c * 8 + r) << 7) + ((ss ^ r) << 3), dst + (c << 9));
    }
  };
  auto instage = [&](int it) {
    int kz = it / 3, ky = it - kz * 3;
    int zi = z + kz - 1, yi = y + ky - 1;
    if (zi >= 0 && zi < 8 && yi >= 0 && yi < 128) {
      const short* row = h2 + ((size_t)(b * 1024 + zi * 128 + yi) << 14);
#pragma unroll
      for (int i = 0; i < 8; ++i) {
        int x0 = 1 + 4 * (wave * 8 + i);
        int x = x0 + (lane >> 4);
        int c8 = (lane & 15) ^ (x & 15);
        gld_lds16(row + ((x - 1) << 7) + (c8 << 3), inbuf + (x0 << 7));
      }
    } else {
#pragma unroll
      for (int i = 0; i < 8; ++i)
        *(bf16x8*)(&inbuf[128 + (i * 256 + tid) * 8]) = zz;
    }
  };

  if (tid < 32) {                             // halo rows 0,129 zero (persist)
    int hf = tid >> 4, u = tid & 15;
    *(bf16x8*)(&inbuf[(hf ? 129 : 0) * 128 + u * 8]) = zz;
  }
  wstage(0);
  instage(0);
  __syncthreads();

  float4 xv[8];
  for (int s = 0; s < 54; ++s) {
    const int it6 = s / 6, sub = s - it6 * 6, kx = sub >> 1, ch2 = sub & 1;
    if (s < 53) wstage(s + 1);
    if (s == 51) {                            // prefetch fp32 res row to regs
      const float* xb = xin + (size_t)b * 8388608 + (size_t)z * 16384 + (size_t)y * 128;
#pragma unroll
      for (int i = 0; i < 8; ++i) {
        int e = i * 256 + tid;
        int ci = e >> 5, x4 = e & 31;
        xv[i] = *(const float4*)(xb + (size_t)ci * 131072 + x4 * 4);
      }
    }
    const short* w = sm + 16640 + ((s & 1) << 13);
#pragma unroll
    for (int chL = 0; chL < 2; ++chL) {
      const int ch = ch2 * 2 + chL;
      bf16x8 af[4], bb[4];
#pragma unroll
      for (int i = 0; i < 4; ++i)
        af[i] = *(const bf16x8*)(&w[(wm * 64 + i * 16 + n0) * 64 + (((chL * 4 + q) ^ (n0 & 7)) << 3)]);
#pragma unroll
      for (int j = 0; j < 4; ++j) {
        int xx = wn * 64 + j * 16 + n0 + kx;
        bb[j] = *(const bf16x8*)(&inbuf[(xx << 7) + (((ch * 4 + q) ^ (xx & 15)) << 3)]);
      }
#pragma unroll
      for (int i = 0; i < 4; ++i)
#pragma unroll
        for (int j = 0; j < 4; ++j)
          acc[i][j] = __builtin_amdgcn_mfma_f32_16x16x32_bf16(af[i], bb[j], acc[i][j], 0, 0, 0);
    }
    __syncthreads();
    if (sub == 5 && it6 < 8) {                // iter boundary: restage input row
      instage(it6 + 1);
      __syncthreads();
    }
  }
  // res 1x1 tap: write x row (bf16, 64-ci 8-unit swizzle) into free weight buf
  short* rbuf = sm + 16640;                   // s=53 read parity 1; buf 0 free
  {
#pragma unroll
    for (int i = 0; i < 8; ++i) {
      int e = i * 256 + tid;
      int ci = e >> 5, x4 = e & 31;
      int u0 = ci >> 3, cl = ci & 7;
#pragma unroll
      for (int k = 0; k < 4; ++k) {
        int xx = x4 * 4 + k;
        float fv = (k == 0) ? xv[i].x : (k == 1) ? xv[i].y : (k == 2) ? xv[i].z : xv[i].w;
        rbuf[xx * 64 + ((u0 ^ (xx & 7)) << 3) + cl] = f2bf(fv);
      }
    }
  }
  __syncthreads();
#pragma unroll
  for (int ch = 0; ch < 2; ++ch) {
    bf16x8 af[4], bb[4];
#pragma unroll
    for (int i = 0; i < 4; ++i)
      af[i] = *(const bf16x8*)(rw + (wm * 64 + i * 16 + n0) * 64 + ch * 32 + q * 8);
#pragma unroll
    for (int j = 0; j < 4; ++j) {
      int xx = wn * 64 + j * 16 + n0;
      bb[j] = *(const bf16x8*)(&rbuf[xx * 64 + (((ch * 4 + q) ^ (xx & 7)) << 3)]);
    }
#pragma unroll
    for (int i = 0; i < 4; ++i)
#pragma unroll
      for (int j = 0; j < 4; ++j)
        acc[i][j] = __builtin_amdgcn_mfma_f32_16x16x32_bf16(af[i], bb[j], acc[i][j], 0, 0, 0);
  }
  __syncthreads();
  // epilogue: + res_b, swish, bf16 out (channels-last)
#pragma unroll
  for (int i = 0; i < 4; ++i) {
    const int mb = wm * 64 + i * 16 + q * 4;
    const float4 bias = *(const float4*)(res_b + mb);
#pragma unroll
    for (int j = 0; j < 4; ++j) {
      const int n = wn * 64 + j * 16 + n0;
      bf16x4v pk;
      pk.x = f2bf(swish_f(acc[i][j][0] + bias.x));
      pk.y = f2bf(swish_f(acc[i][j][1] + bias.y));
      pk.z = f2bf(swish_f(acc[i][j][2] + bias.z));
      pk.w = f2bf(swish_f(acc[i][j][3] + bias.w));
      *(bf16x4v*)(&sm[n * 136 + mb]) = pk;
    }
  }
  __syncthreads();
  short* orow = h3 + (size_t)gid * 16384;
#pragma unroll
  for (int i = 0; i < 8; ++i) {
    int e = i * 256 + tid;
    int xx = e >> 4, c8 = e & 15;
    *(bf16x8*)(orow + e * 8) = *(const bf16x8*)(&sm[xx * 136 + c8 * 8]);
  }
}

// ------------------------------------------------------------------
// down: out = conv3d(h3, down_w, stride (1,2,2), pad z only) + down_b, fp32 NCDHW
__global__ __launch_bounds__(256, 2) void down_kernel(
    const short* __restrict__ h3, const short* __restrict__ wt,
    const float* __restrict__ dnb, float* __restrict__ out) {
  __shared__ __align__(16) short sm[33024];   // inbuf 16640 + wbuf 2*8192
  const int tid = threadIdx.x;
  const int bi = blockIdx.x;                  // 4*8*63 = 2016
  const int o = (bi & 7) * 252 + (bi >> 3);
  const int yo = o % 63;
  const int zb = o / 63;
  const int z = zb & 7, b = zb >> 3;
  const int lane = tid & 63, wave = tid >> 6;
  const int wm = wave >> 1, wn = wave & 1;
  const int q = lane >> 4, n0 = lane & 15;
  const bf16x8 zz = {0, 0, 0, 0, 0, 0, 0, 0};
  short* inbuf = sm;                          // [130 x][128 ci], rows 0..127 data
  f32x4 acc[4][2];
#pragma unroll
  for (int i = 0; i < 4; ++i)
#pragma unroll
    for (int j = 0; j < 2; ++j) acc[i][j] = (f32x4){0.f, 0.f, 0.f, 0.f};

  auto wstage = [&](int s) {
    int it6 = s / 6, sub = s - it6 * 6, kx = sub >> 1, ch2 = sub & 1;
    const short* src = wt + (((it6 * 3 + kx) << 14) + (ch2 << 6));
    short* dst = sm + 16640 + ((s & 1) << 13);
    int r = lane >> 3, ss = lane & 7;
#pragma unroll
    for (int i = 0; i < 4; ++i) {
      int c = wave * 4 + i;
      gld_lds16(src + ((c * 8 + r) << 7) + ((ss ^ r) << 3), dst + (c << 9));
    }
  };
  auto instage = [&](int it) {
    int kz = it / 3, ky = it - kz * 3;
    int zi = z + kz - 1;
    int yi = 2 * yo + ky;                     // always in range
    if (zi >= 0 && zi < 8) {
      const short* row = h3 + ((size_t)(b * 1024 + zi * 128 + yi) << 14);
#pragma unroll
      for (int i = 0; i < 8; ++i) {
        int x0 = 4 * (wave * 8 + i);          // no x shift
        int x = x0 + (lane >> 4);
        int c8 = (lane & 15) ^ (x & 15);
        gld_lds16(row + (x << 7) + (c8 << 3), inbuf + (x0 << 7));
      }
    } else {
#pragma unroll
      for (int i = 0; i < 8; ++i)
        *(bf16x8*)(&inbuf[(i * 256 + tid) * 8]) = zz;
    }
  };

  if (tid < 32) {                             // rows 128,129 zero (dead n=63 lanes)
    int hf = tid >> 4, u = tid & 15;
    *(bf16x8*)(&inbuf[(128 + hf) * 128 + u * 8]) = zz;
  }
  wstage(0);
  instage(0);
  __syncthreads();

  for (int s = 0; s < 54; ++s) {
    const int it6 = s / 6, sub = s - it6 * 6, kx = sub >> 1, ch2 = sub & 1;
    if (s < 53) wstage(s + 1);
    const short* w = sm + 16640 + ((s & 1) << 13);
#pragma unroll
    for (int chL = 0; chL < 2; ++chL) {
      const int ch = ch2 * 2 + chL;
      bf16x8 af[4], bb[2];
#pragma unroll
      for (int i = 0; i < 4; ++i)
        af[i] = *(const bf16x8*)(&w[(wm * 64 + i * 16 + n0) * 64 + (((chL * 4 + q) ^ (n0 & 7)) << 3)]);
#pragma unroll
      for (int j = 0; j < 2; ++j) {
        int xp = 2 * (wn * 32 + j * 16 + n0) + kx;
        bb[j] = *(const bf16x8*)(&inbuf[(xp << 7) + (((ch * 4 + q) ^ (xp & 15)) << 3)]);
      }
#pragma unroll
      for (int i = 0; i < 4; ++i)
#pragma unroll
        for (int j = 0; j < 2; ++j)
          acc[i][j] = __builtin_amdgcn_mfma_f32_16x16x32_bf16(af[i], bb[j], acc[i][j], 0, 0, 0);
    }
    __syncthreads();
    if (sub == 5 && it6 < 8) {
      instage(it6 + 1);
      __syncthreads();
    }
  }
  // epilogue: + down_b, fp32 transpose in LDS, channels-first NCDHW out
  float* fsm = (float*)sm;
#pragma unroll
  for (int i = 0; i < 4; ++i) {
    const int mb = wm * 64 + i * 16 + q * 4;
    const float4 bias = *(const float4*)(dnb + mb);
#pragma unroll
    for (int j = 0; j < 2; ++j) {
      const int n = wn * 32 + j * 16 + n0;
      f32x4 v;
      v[0] = acc[i][j][0] + bias.x;
      v[1] = acc[i][j][1] + bias.y;
      v[2] = acc[i][j][2] + bias.z;
      v[3] = acc[i][j][3] + bias.w;
      *(f32x4*)(&fsm[n * 132 + mb]) = v;
    }
  }
  __syncthreads();
#pragma unroll
  for (int it = 0; it < 32; ++it) {           // 128 co x 64 lanes (63 valid)
    int idx = it * 256 + tid;
    int co = idx >> 6, xl = idx & 63;
    if (xl < 63)
      out[((size_t)(b * 128 + co) * 8 + z) * 3969 + yo * 63 + xl] = fsm[xl * 132 + co];
  }
}

// ------------------------------------------------------------------
extern "C" void kernel_launch(void* const* d_in, const int* in_sizes, int n_in,
                              void* d_out, int out_size, void* d_ws, size_t ws_size,
                              hipStream_t stream) {
  const float* x       = (const float*)d_in[0];
  const float* embed   = (const float*)d_in[1];
  const float* context = (const float*)d_in[2];
  const float* w20     = (const float*)d_in[3];
  const float* b20     = (const float*)d_in[4];
  const float* w21     = (const float*)d_in[5];
  const float* d1w     = (const float*)d_in[6];
  const float* d1b     = (const float*)d_in[7];
  const float* d2w     = (const float*)d_in[8];
  const float* d2b     = (const float*)d_in[9];
  const float* resw    = (const float*)d_in[10];
  const float* resb    = (const float*)d_in[11];
  const float* dnw     = (const float*)d_in[12];
  const float* dnb     = (const float*)d_in[13];
  float* out = (float*)d_out;
  char* ws = (char*)d_ws;
  float* s1   = (float*)(ws + 0);          // 1 KB
  float* s2   = (float*)(ws + 1024);       // 2 KB
  short* wt20 = (short*)(ws + 4096);       // 432 KB
  short* wt21 = (short*)(ws + 446464);     // 864 KB
  short* wtdn = (short*)(ws + 1331200);    // 864 KB
  short* rw   = (short*)(ws + 2215936);    // 16 KB
  short* h1   = (short*)(ws + 2232320);    // 64 MB  [b][z][y][x][ci=64] bf16
  short* h2   = (short*)(ws + 69341184);   // 128 MB [b][z][y][x][ci=128] bf16
  short* h3   = (short*)(ws + 203558912);  // 128 MB [b][z][y][x][ci=128] bf16

  scales_kernel<<<3, 256, 0, stream>>>(embed, context, d1w, d1b, d2w, d2b, s1, s2);
  prep_w_kernel<<<1088, 256, 0, stream>>>(w20, w21, dnw, resw, wt20, wt21, wtdn, rw);
  prep_h1_kernel<<<4096, 256, 0, stream>>>(x, s1, h1);
  conv20_kernel<<<4096, 256, 0, stream>>>(h1, wt20, b20, s2, h2);
  conv21_kernel<<<4096, 256, 0, stream>>>(h2, wt21, x, rw, resb, h3);
  down_kernel<<<2016, 256, 0, stream>>>(h3, wtdn, dnb, out);
}